// Round 7
// baseline (2472.419 us; speedup 1.0000x reference)
//
#include <hip/hip_runtime.h>

#define S 512
#define B 256
#define D 128
#define H1 128
#define H2 256

#define NGRP 8
#define BG 32
#define WPG 10
#define NWG 80

// byte offsets in ws
#define OFF_XPROJ 0u          // [B][512] f32 = 524288
#define OFF_H1HI  524288u     // [4][B][H1] bf16 = 262144
#define OFF_H1LO  786432u     // 262144
#define OFF_H2HI  1048576u    // [4][B][H2] bf16 = 524288
#define OFF_H2LO  1572864u    // 524288
#define OFF_OUTP  2097152u    // [S][8][B] f32 = 4194304
#define OFF_TAGS  6291456u    // 8 grp * 64 int

#define DYN_LDS 67072

typedef unsigned long long ull;
typedef unsigned short ushort;
typedef __attribute__((ext_vector_type(8))) short short8;
typedef __attribute__((ext_vector_type(4))) float f32x4;

__device__ __forceinline__ ushort f2bf(float f){
  unsigned u = __float_as_uint(f);
  unsigned r = u + 0x7fffu + ((u>>16)&1u);
  return (ushort)(r>>16);
}
__device__ __forceinline__ float rcpf_(float x){ return __builtin_amdgcn_rcpf(x); }
__device__ __forceinline__ float sigm(float x){ return rcpf_(1.f + __expf(-x)); }
__device__ __forceinline__ float tanh_(float x){ return 1.f - 2.f*rcpf_(1.f + __expf(2.f*x)); }

__device__ __forceinline__ void ast8(ull* p, ull v){
  __hip_atomic_store(p, v, __ATOMIC_RELAXED, __HIP_MEMORY_SCOPE_AGENT);
}
__device__ __forceinline__ ull ald8(const ull* p){
  return __hip_atomic_load(p, __ATOMIC_RELAXED, __HIP_MEMORY_SCOPE_AGENT);
}
__device__ __forceinline__ int aldi(const int* p){
  return __hip_atomic_load(p, __ATOMIC_RELAXED, __HIP_MEMORY_SCOPE_AGENT);
}
__device__ __forceinline__ ull pk4(ushort a, ushort b, ushort c, ushort d){
  return (ull)a | ((ull)b<<16) | ((ull)c<<32) | ((ull)d<<48);
}

__global__ void k_zero(char* wsb){
  long long id = (long long)blockIdx.x*blockDim.x + threadIdx.x;
  long long stride = (long long)gridDim.x*blockDim.x;
  ull* h = (ull*)(wsb + OFF_H1HI);           // h1hi..h2lo contiguous: 1572864 B
  for (long long i = id; i < 196608; i += stride) h[i] = 0ull;
  ull* f = (ull*)(wsb + OFF_TAGS);
  for (long long i = id; i < 256; i += stride) f[i] = 0ull;
}

__global__ void k_xproj(const float* __restrict__ x, const float* __restrict__ Wih1,
                        const float* __restrict__ bih1, const float* __restrict__ bhh1,
                        char* __restrict__ wsb){
  __shared__ float xs[D];
  float* xproj = (float*)(wsb + OFF_XPROJ);
  int b = blockIdx.x;
  for (int d = threadIdx.x; d < D; d += blockDim.x) xs[d] = x[b*D + d];
  __syncthreads();
  for (int g = threadIdx.x; g < 4*H1; g += blockDim.x){
    float acc = bih1[g] + bhh1[g];
    const float* w = &Wih1[(size_t)g*D];
    #pragma unroll 8
    for (int d = 0; d < D; ++d) acc += xs[d]*w[d];
    xproj[(size_t)b*512 + g] = acc;
  }
}

// wait until tags[lo..hi) >= need (wave 0 polls, then WG rendezvous)
__device__ __forceinline__ void wait_tags(const int* tags, int t, int lo, int hi, int need){
  if (t < 64){
    for(;;){
      int f = (t >= lo && t < hi) ? aldi(&tags[t]) : 0x7fffffff;
      if (__all(f >= need)) break;
      __builtin_amdgcn_s_sleep(1);
    }
  }
  __syncthreads();
}
// L1 wait: L1 tags (0..8) >= r for data; L2 tags (8..40) >= r-2 for write-safety
__device__ __forceinline__ void wait_l1(const int* tags, int t, int r){
  if (t < 64){
    int need = (t < 8) ? r : (r-2);
    for(;;){
      int f = (t < 40) ? aldi(&tags[t]) : 0x7fffffff;
      if (__all(f >= need)) break;
      __builtin_amdgcn_s_sleep(1);
    }
  }
  __syncthreads();
}
// per-wave tag publish: drain this wave's stores, lane 0 stores tag
__device__ __forceinline__ void publish(int* tags, int slot, int lane, int v){
  asm volatile("s_waitcnt vmcnt(0)" ::: "memory");
  if (lane == 0)
    __hip_atomic_store(&tags[slot], v, __ATOMIC_RELAXED, __HIP_MEMORY_SCOPE_AGENT);
}

__global__ void __launch_bounds__(256,1)
k_persist(const float* __restrict__ Whh1,
          const float* __restrict__ Wih2, const float* __restrict__ Whh2,
          const float* __restrict__ bih2, const float* __restrict__ bhh2,
          const float* __restrict__ Wout,
          char* __restrict__ wsb){
  extern __shared__ char sm[];
  const int wg = blockIdx.x;
  const int t  = threadIdx.x;
  const int grp = wg / WPG, role = wg % WPG;
  const int gb0 = grp * BG;
  const int l = t & 63, wv = t >> 6, lr = l & 15, lk = (l >> 4) * 8;

  float* xproj = (float*)(wsb + OFF_XPROJ);
  ull* h1hi = (ull*)(wsb + OFF_H1HI);   // [4][B][H1] bf16 -> 8192 ull per buf
  ull* h1lo = (ull*)(wsb + OFF_H1LO);
  ull* h2hi = (ull*)(wsb + OFF_H2HI);   // [4][B][H2] bf16 -> 16384 ull per buf
  ull* h2lo = (ull*)(wsb + OFF_H2LO);
  float* outp = (float*)(wsb + OFF_OUTP);
  int* tags = (int*)(wsb + OFF_TAGS) + grp*64;

  if (role < 2){
    // ================= layer-1 WG: 64 units, 32 batches =================
    const int u0 = role * 64;
    ushort* hsH = (ushort*)sm;            // [32][136] bf16
    ushort* hsL = (ushort*)(sm + 8704);   // [32][136]
    float*  gl  = (float*)(sm + 17408);   // [32][260] f32 gates
    const int slot = role*4 + wv;

    short8 bhi[4][4], blo[4][4];
    #pragma unroll
    for (int kt=0;kt<4;++kt){
      #pragma unroll
      for (int ct=0;ct<4;++ct){
        int col = wv*64 + ct*16 + lr;
        int lu = col>>2, g = col&3;
        const float* src = Whh1 + (size_t)(g*H1 + u0 + lu)*D + kt*32 + lk;
        short8 vh, vl;
        #pragma unroll
        for (int j=0;j<8;++j){
          float w = src[j];
          ushort hb = f2bf(w);
          float hf = __uint_as_float((unsigned)hb<<16);
          vh[j] = (short)hb; vl[j] = (short)f2bf(w - hf);
        }
        bhi[kt][ct]=vh; blo[kt][ct]=vl;
      }
    }
    f32x4 xpf[2][4];
    #pragma unroll
    for (int bt=0;bt<2;++bt){
      #pragma unroll
      for (int ct=0;ct<4;++ct){
        int col = wv*64 + ct*16 + lr;
        int lu = col>>2, g = col&3;
        #pragma unroll
        for (int q=0;q<4;++q){
          int b = gb0 + bt*16 + (l>>4)*4 + q;
          xpf[bt][ct][q] = xproj[(size_t)b*512 + g*H1 + u0 + lu];
        }
      }
    }
    const int nb = t>>3, lu0 = (t&7)*8;
    float c1[8];
    #pragma unroll
    for (int j=0;j<8;++j) c1[j]=0.f;

    for (int r=0; r<S; ++r){
      if (r>0) wait_l1(tags, t, r);
      {
        const int rb = (r-1)&3, wb = r&3;
        const ull* sH = h1hi + (size_t)rb*8192;
        const ull* sL = h1lo + (size_t)rb*8192;
        ull tH[4], tL[4];
        #pragma unroll
        for (int m=0;m<4;++m){
          int id = t + m*256;
          int b = id>>5, k4 = id&31;
          size_t go = (size_t)(gb0+b)*32 + k4;
          tH[m] = ald8(sH+go);
          tL[m] = ald8(sL+go);
        }
        #pragma unroll
        for (int m=0;m<4;++m){
          int id = t + m*256;
          int b = id>>5, k4 = id&31;
          *(ull*)(hsH + b*136 + k4*4) = tH[m];
          *(ull*)(hsL + b*136 + k4*4) = tL[m];
        }
        __syncthreads();
        f32x4 acc[2][4];
        #pragma unroll
        for (int bt=0;bt<2;++bt){
          #pragma unroll
          for (int ct=0;ct<4;++ct) acc[bt][ct]=xpf[bt][ct];
        }
        #pragma unroll
        for (int kt=0;kt<4;++kt){
          short8 ah[2], al[2];
          #pragma unroll
          for (int bt=0;bt<2;++bt){
            int off = (bt*16+lr)*136 + kt*32 + lk;
            ah[bt] = *(const short8*)(hsH + off);
            al[bt] = *(const short8*)(hsL + off);
          }
          #pragma unroll
          for (int bt=0;bt<2;++bt){
            #pragma unroll
            for (int ct=0;ct<4;++ct){
              acc[bt][ct] = __builtin_amdgcn_mfma_f32_16x16x32_bf16(ah[bt], bhi[kt][ct], acc[bt][ct],0,0,0);
              acc[bt][ct] = __builtin_amdgcn_mfma_f32_16x16x32_bf16(al[bt], bhi[kt][ct], acc[bt][ct],0,0,0);
              acc[bt][ct] = __builtin_amdgcn_mfma_f32_16x16x32_bf16(ah[bt], blo[kt][ct], acc[bt][ct],0,0,0);
            }
          }
        }
        #pragma unroll
        for (int bt=0;bt<2;++bt){
          #pragma unroll
          for (int ct=0;ct<4;++ct){
            #pragma unroll
            for (int q=0;q<4;++q)
              gl[(bt*16 + (l>>4)*4 + q)*260 + wv*64 + ct*16 + lr] = acc[bt][ct][q];
          }
        }
        __syncthreads();
        float hv[8];
        #pragma unroll
        for (int j=0;j<8;++j){
          f32x4 gv = *(const f32x4*)&gl[nb*260 + (lu0+j)*4];
          float ig = sigm(gv[0]), fg = sigm(gv[1]);
          float gg = tanh_(gv[2]), og = sigm(gv[3]);
          c1[j] = fg*c1[j] + ig*gg;
          hv[j] = og*tanh_(c1[j]);
        }
        ushort hb[8], lb[8];
        #pragma unroll
        for (int j=0;j<8;++j){
          hb[j] = f2bf(hv[j]);
          float hf = __uint_as_float((unsigned)hb[j]<<16);
          lb[j] = f2bf(hv[j]-hf);
        }
        size_t db = (size_t)wb*8192 + (size_t)(gb0+nb)*32 + ((u0+lu0)>>2);
        ast8(h1hi+db,   pk4(hb[0],hb[1],hb[2],hb[3]));
        ast8(h1hi+db+1, pk4(hb[4],hb[5],hb[6],hb[7]));
        ast8(h1lo+db,   pk4(lb[0],lb[1],lb[2],lb[3]));
        ast8(h1lo+db+1, pk4(lb[4],lb[5],lb[6],lb[7]));
        publish(tags, slot, l, r+1);
      }
    }
  } else {
    // ================= layer-2 WG: 32 units, 32 batches =================
    const int us = role - 2;
    const int u0 = us * 32;
    ushort* hcH = (ushort*)sm;             // [32][392] bf16
    ushort* hcL = (ushort*)(sm + 25088);   // [32][392]
    float*  gl  = (float*)(sm + 50176);    // [32][132] f32 gates
    const int slot = 8 + us*4 + wv;

    short8 bhi[12][2], blo[12][2];
    #pragma unroll
    for (int kt=0;kt<12;++kt){
      #pragma unroll
      for (int ct=0;ct<2;++ct){
        int col = wv*32 + ct*16 + lr;
        int lu = col>>2, g = col&3;
        int row = g*H2 + u0 + lu;
        const float* src = (kt<4) ? (Wih2 + (size_t)row*D + kt*32 + lk)
                                  : (Whh2 + (size_t)row*H2 + (kt-4)*32 + lk);
        short8 vh, vl;
        #pragma unroll
        for (int j=0;j<8;++j){
          float w = src[j];
          ushort hb = f2bf(w);
          float hf = __uint_as_float((unsigned)hb<<16);
          vh[j] = (short)hb; vl[j] = (short)f2bf(w - hf);
        }
        bhi[kt][ct]=vh; blo[kt][ct]=vl;
      }
    }
    float biasv[2];
    #pragma unroll
    for (int ct=0;ct<2;++ct){
      int col = wv*32 + ct*16 + lr;
      int lu = col>>2, g = col&3;
      biasv[ct] = bih2[g*H2+u0+lu] + bhh2[g*H2+u0+lu];
    }
    const int nb = t>>3, lu0 = (t&7)*4;
    float wo[4];
    #pragma unroll
    for (int j=0;j<4;++j) wo[j] = Wout[u0+lu0+j];
    float c2[4] = {0.f,0.f,0.f,0.f};

    for (int r=0; r<=S; ++r){
      if (r>=1){
        const int ts = r-1;
        // ---- phase A: h1[r-1] (ready early; L1 runs ahead) ----
        wait_tags(tags, t, 0, 8, r);
        const ull* s1H = h1hi + (size_t)((r-1)&3)*8192;
        const ull* s1L = h1lo + (size_t)((r-1)&3)*8192;
        ull t1H[4], t1L[4];
        #pragma unroll
        for (int m=0;m<4;++m){
          int id = t + m*256;
          int b = id>>5, s = id&31;
          size_t go = (size_t)(gb0+b)*32 + s;
          t1H[m] = ald8(s1H+go);
          t1L[m] = ald8(s1L+go);
        }
        #pragma unroll
        for (int m=0;m<4;++m){
          int id = t + m*256;
          int b = id>>5, s = id&31;
          *(ull*)(hcH + b*392 + s*4) = t1H[m];
          *(ull*)(hcL + b*392 + s*4) = t1L[m];
        }
        __syncthreads();
        f32x4 acc[2][2];
        #pragma unroll
        for (int bt=0;bt<2;++bt){
          #pragma unroll
          for (int ct=0;ct<2;++ct){
            f32x4 a; a[0]=biasv[ct]; a[1]=biasv[ct]; a[2]=biasv[ct]; a[3]=biasv[ct];
            acc[bt][ct]=a;
          }
        }
        #pragma unroll
        for (int kt=0;kt<4;++kt){
          short8 ah[2], al[2];
          #pragma unroll
          for (int bt=0;bt<2;++bt){
            int off = (bt*16+lr)*392 + kt*32 + lk;
            ah[bt] = *(const short8*)(hcH + off);
            al[bt] = *(const short8*)(hcL + off);
          }
          #pragma unroll
          for (int bt=0;bt<2;++bt){
            #pragma unroll
            for (int ct=0;ct<2;++ct){
              acc[bt][ct] = __builtin_amdgcn_mfma_f32_16x16x32_bf16(ah[bt], bhi[kt][ct], acc[bt][ct],0,0,0);
              acc[bt][ct] = __builtin_amdgcn_mfma_f32_16x16x32_bf16(al[bt], bhi[kt][ct], acc[bt][ct],0,0,0);
              acc[bt][ct] = __builtin_amdgcn_mfma_f32_16x16x32_bf16(ah[bt], blo[kt][ct], acc[bt][ct],0,0,0);
            }
          }
        }
        // ---- phase B: h2[r-2] from peers ----
        wait_tags(tags, t, 8, 40, r);
        const ull* s2H = h2hi + (size_t)((r-2)&3)*16384;
        const ull* s2L = h2lo + (size_t)((r-2)&3)*16384;
        ull t2H[8], t2L[8];
        #pragma unroll
        for (int m=0;m<8;++m){
          int id = t + m*256;
          int b = id>>6, s = id&63;
          size_t go = (size_t)(gb0+b)*64 + s;
          t2H[m] = ald8(s2H+go);
          t2L[m] = ald8(s2L+go);
        }
        #pragma unroll
        for (int m=0;m<8;++m){
          int id = t + m*256;
          int b = id>>6, s = id&63;
          *(ull*)(hcH + b*392 + 128 + s*4) = t2H[m];
          *(ull*)(hcL + b*392 + 128 + s*4) = t2L[m];
        }
        __syncthreads();
        #pragma unroll
        for (int kt=4;kt<12;++kt){
          short8 ah[2], al[2];
          #pragma unroll
          for (int bt=0;bt<2;++bt){
            int off = (bt*16+lr)*392 + kt*32 + lk;
            ah[bt] = *(const short8*)(hcH + off);
            al[bt] = *(const short8*)(hcL + off);
          }
          #pragma unroll
          for (int bt=0;bt<2;++bt){
            #pragma unroll
            for (int ct=0;ct<2;++ct){
              acc[bt][ct] = __builtin_amdgcn_mfma_f32_16x16x32_bf16(ah[bt], bhi[kt][ct], acc[bt][ct],0,0,0);
              acc[bt][ct] = __builtin_amdgcn_mfma_f32_16x16x32_bf16(al[bt], bhi[kt][ct], acc[bt][ct],0,0,0);
              acc[bt][ct] = __builtin_amdgcn_mfma_f32_16x16x32_bf16(ah[bt], blo[kt][ct], acc[bt][ct],0,0,0);
            }
          }
        }
        #pragma unroll
        for (int bt=0;bt<2;++bt){
          #pragma unroll
          for (int ct=0;ct<2;++ct){
            #pragma unroll
            for (int q=0;q<4;++q)
              gl[(bt*16 + (l>>4)*4 + q)*132 + wv*32 + ct*16 + lr] = acc[bt][ct][q];
          }
        }
        __syncthreads();
        float psum = 0.f;
        ushort hb[4], lb[4];
        #pragma unroll
        for (int j=0;j<4;++j){
          f32x4 gv = *(const f32x4*)&gl[nb*132 + (lu0+j)*4];
          float ig = sigm(gv[0]), fg = sigm(gv[1]);
          float gg = tanh_(gv[2]), og = sigm(gv[3]);
          c2[j] = fg*c2[j] + ig*gg;
          float h = og*tanh_(c2[j]);
          psum += h*wo[j];
          hb[j] = f2bf(h);
          lb[j] = f2bf(h - __uint_as_float((unsigned)hb[j]<<16));
        }
        size_t db = (size_t)((r-1)&3)*16384 + (size_t)(gb0+nb)*64 + ((u0+lu0)>>2);
        ast8(h2hi+db, pk4(hb[0],hb[1],hb[2],hb[3]));
        ast8(h2lo+db, pk4(lb[0],lb[1],lb[2],lb[3]));
        publish(tags, slot, l, r+1);
        // off critical path: output projection partial
        psum += __shfl_xor(psum,1,64);
        psum += __shfl_xor(psum,2,64);
        psum += __shfl_xor(psum,4,64);
        if ((t&7)==0) outp[(size_t)ts*2048 + us*256 + gb0+nb] = psum;
      } else {
        publish(tags, slot, l, 1);
      }
    }
  }
}

__global__ void k_final(const char* __restrict__ wsb, const float* __restrict__ bout,
                        float* __restrict__ out){
  const float* outp = (const float*)(wsb + OFF_OUTP);
  int id = blockIdx.x*blockDim.x + threadIdx.x;
  if (id >= B*S) return;
  int tt = id >> 8;
  int b  = id & 255;
  float s = bout[0];
  const float* p = outp + (size_t)tt*2048 + b;
  #pragma unroll
  for (int u = 0; u < 8; ++u) s += p[(size_t)u*256];
  out[(size_t)b*S + tt] = s;
}

extern "C" void kernel_launch(void* const* d_in, const int* in_sizes, int n_in,
                              void* d_out, int out_size, void* d_ws, size_t ws_size,
                              hipStream_t stream){
  const float* x    = (const float*)d_in[0];
  const float* Wih1 = (const float*)d_in[1];
  const float* Whh1 = (const float*)d_in[2];
  const float* bih1 = (const float*)d_in[3];
  const float* bhh1 = (const float*)d_in[4];
  const float* Wih2 = (const float*)d_in[5];
  const float* Whh2 = (const float*)d_in[6];
  const float* bih2 = (const float*)d_in[7];
  const float* bhh2 = (const float*)d_in[8];
  const float* Wout = (const float*)d_in[9];
  const float* bout = (const float*)d_in[10];
  char* wsb  = (char*)d_ws;
  float* out = (float*)d_out;

  (void)hipFuncSetAttribute((const void*)k_persist,
                            hipFuncAttributeMaxDynamicSharedMemorySize, DYN_LDS);

  k_zero<<<dim3(64), dim3(256), 0, stream>>>(wsb);
  k_xproj<<<dim3(B), dim3(256), 0, stream>>>(x, Wih1, bih1, bhh1, wsb);
  k_persist<<<dim3(NWG), dim3(256), DYN_LDS, stream>>>(Whh1, Wih2, Whh2, bih2, bhh2, Wout, wsb);
  k_final<<<dim3((B*S)/256), dim3(256), 0, stream>>>(wsb, bout, out);
}

// Round 8
// 1970.580 us; speedup vs baseline: 1.2547x; 1.2547x over previous
//
#include <hip/hip_runtime.h>

#define S 512
#define B 256
#define D 128
#define H1 128
#define H2 256

#define NGRP 8
#define BG 32
#define WPG 10
#define NWG 80

// byte offsets in ws
#define OFF_XPROJ 0u          // [B][512] f32 = 524288
#define OFF_H1HI  524288u     // [4][B][H1] bf16 = 262144
#define OFF_H1LO  786432u     // 262144
#define OFF_H2HI  1048576u    // [4][B][H2] bf16 = 524288
#define OFF_H2LO  1572864u    // 524288
#define OFF_OUTP  2097152u    // [S][8][B] f32 = 4194304
#define OFF_FLAG  6291456u    // 8 grp * 32 int (one 128B line each)

#define DYN_LDS 67072

typedef unsigned long long ull;
typedef unsigned short ushort;
typedef __attribute__((ext_vector_type(8))) short short8;
typedef __attribute__((ext_vector_type(4))) float f32x4;

__device__ __forceinline__ ushort f2bf(float f){
  unsigned u = __float_as_uint(f);
  unsigned r = u + 0x7fffu + ((u>>16)&1u);
  return (ushort)(r>>16);
}
__device__ __forceinline__ float rcpf_(float x){ return __builtin_amdgcn_rcpf(x); }
__device__ __forceinline__ float sigm(float x){ return rcpf_(1.f + __expf(-x)); }
__device__ __forceinline__ float tanh_(float x){ return 1.f - 2.f*rcpf_(1.f + __expf(2.f*x)); }

__device__ __forceinline__ void ast8(ull* p, ull v){
  __hip_atomic_store(p, v, __ATOMIC_RELAXED, __HIP_MEMORY_SCOPE_AGENT);
}
__device__ __forceinline__ ull ald8(const ull* p){
  return __hip_atomic_load(p, __ATOMIC_RELAXED, __HIP_MEMORY_SCOPE_AGENT);
}
__device__ __forceinline__ int aldi(const int* p){
  return __hip_atomic_load(p, __ATOMIC_RELAXED, __HIP_MEMORY_SCOPE_AGENT);
}
__device__ __forceinline__ ull pk4(ushort a, ushort b, ushort c, ushort d){
  return (ull)a | ((ull)b<<16) | ((ull)c<<32) | ((ull)d<<48);
}

__global__ void k_zero(char* wsb){
  long long id = (long long)blockIdx.x*blockDim.x + threadIdx.x;
  long long stride = (long long)gridDim.x*blockDim.x;
  ull* h = (ull*)(wsb + OFF_H1HI);           // h1hi..h2lo contiguous: 1572864 B
  for (long long i = id; i < 196608; i += stride) h[i] = 0ull;
  ull* f = (ull*)(wsb + OFF_FLAG);
  for (long long i = id; i < 256; i += stride) f[i] = 0ull;
}

__global__ void k_xproj(const float* __restrict__ x, const float* __restrict__ Wih1,
                        const float* __restrict__ bih1, const float* __restrict__ bhh1,
                        char* __restrict__ wsb){
  __shared__ float xs[D];
  float* xproj = (float*)(wsb + OFF_XPROJ);
  int b = blockIdx.x;
  for (int d = threadIdx.x; d < D; d += blockDim.x) xs[d] = x[b*D + d];
  __syncthreads();
  for (int g = threadIdx.x; g < 4*H1; g += blockDim.x){
    float acc = bih1[g] + bhh1[g];
    const float* w = &Wih1[(size_t)g*D];
    #pragma unroll 8
    for (int d = 0; d < D; ++d) acc += xs[d]*w[d];
    xproj[(size_t)b*512 + g] = acc;
  }
}

// L1 wait: L1 flags (slot 0,1) >= r for h1 data; L2 flags (2..9) >= r-2 for
// write-safety (4-deep buffer). Lets L1 run up to 2 rounds ahead.
__device__ __forceinline__ void wait_l1(const int* gf, int t, int r){
  if (t < 64){
    int need = (t < 2) ? r : (r-2);
    for(;;){
      int f = (t < 10) ? aldi(&gf[t]) : 0x7fffffff;
      if (__all(f >= need)) break;
      __builtin_amdgcn_s_sleep(1);
    }
  }
  __syncthreads();
}
// L2 wait: all 10 flags >= r (L1 part is pre-satisfied in steady state)
__device__ __forceinline__ void wait_l2(const int* gf, int t, int r){
  if (t < 64){
    for(;;){
      int f = (t < 10) ? aldi(&gf[t]) : 0x7fffffff;
      if (__all(f >= r)) break;
      __builtin_amdgcn_s_sleep(1);
    }
  }
  __syncthreads();
}
// publish: WG rendezvous (drains all waves' stores) then t0 stores flag
__device__ __forceinline__ void flag_done(int* gf, int slot, int t, int v){
  __syncthreads();
  if (t == 0){
    __hip_atomic_store(&gf[slot], v, __ATOMIC_RELAXED, __HIP_MEMORY_SCOPE_AGENT);
  }
}

__global__ void __launch_bounds__(256,1)
k_persist(const float* __restrict__ Whh1,
          const float* __restrict__ Wih2, const float* __restrict__ Whh2,
          const float* __restrict__ bih2, const float* __restrict__ bhh2,
          const float* __restrict__ Wout,
          char* __restrict__ wsb){
  extern __shared__ char sm[];
  const int wg = blockIdx.x;
  const int t  = threadIdx.x;
  const int grp = wg / WPG, role = wg % WPG;
  const int gb0 = grp * BG;
  const int l = t & 63, wv = t >> 6, lr = l & 15, lk = (l >> 4) * 8;

  float* xproj = (float*)(wsb + OFF_XPROJ);
  ull* h1hi = (ull*)(wsb + OFF_H1HI);   // [4][B][H1] bf16 -> 8192 ull per buf
  ull* h1lo = (ull*)(wsb + OFF_H1LO);
  ull* h2hi = (ull*)(wsb + OFF_H2HI);   // [4][B][H2] bf16 -> 16384 ull per buf
  ull* h2lo = (ull*)(wsb + OFF_H2LO);
  float* outp = (float*)(wsb + OFF_OUTP);
  int* gf = (int*)(wsb + OFF_FLAG) + grp*32;

  if (role < 2){
    // ================= layer-1 WG: 64 units, 32 batches =================
    const int u0 = role * 64;
    ushort* hsH = (ushort*)sm;            // [32][136] bf16
    ushort* hsL = (ushort*)(sm + 8704);   // [32][136]
    float*  gl  = (float*)(sm + 17408);   // [32][260] f32 gates

    short8 bhi[4][4], blo[4][4];
    #pragma unroll
    for (int kt=0;kt<4;++kt){
      #pragma unroll
      for (int ct=0;ct<4;++ct){
        int col = wv*64 + ct*16 + lr;
        int lu = col>>2, g = col&3;
        const float* src = Whh1 + (size_t)(g*H1 + u0 + lu)*D + kt*32 + lk;
        short8 vh, vl;
        #pragma unroll
        for (int j=0;j<8;++j){
          float w = src[j];
          ushort hb = f2bf(w);
          float hf = __uint_as_float((unsigned)hb<<16);
          vh[j] = (short)hb; vl[j] = (short)f2bf(w - hf);
        }
        bhi[kt][ct]=vh; blo[kt][ct]=vl;
      }
    }
    f32x4 xpf[2][4];
    #pragma unroll
    for (int bt=0;bt<2;++bt){
      #pragma unroll
      for (int ct=0;ct<4;++ct){
        int col = wv*64 + ct*16 + lr;
        int lu = col>>2, g = col&3;
        #pragma unroll
        for (int q=0;q<4;++q){
          int b = gb0 + bt*16 + (l>>4)*4 + q;
          xpf[bt][ct][q] = xproj[(size_t)b*512 + g*H1 + u0 + lu];
        }
      }
    }
    const int nb = t>>3, lu0 = (t&7)*8;
    float c1[8];
    #pragma unroll
    for (int j=0;j<8;++j) c1[j]=0.f;

    for (int r=0; r<S; ++r){
      if (r>0) wait_l1(gf, t, r);
      const int rb = (r-1)&3, wb = r&3;
      const ull* sH = h1hi + (size_t)rb*8192;
      const ull* sL = h1lo + (size_t)rb*8192;
      ull tH[4], tL[4];
      #pragma unroll
      for (int m=0;m<4;++m){
        int id = t + m*256;
        int b = id>>5, k4 = id&31;
        size_t go = (size_t)(gb0+b)*32 + k4;
        tH[m] = ald8(sH+go);
        tL[m] = ald8(sL+go);
      }
      #pragma unroll
      for (int m=0;m<4;++m){
        int id = t + m*256;
        int b = id>>5, k4 = id&31;
        *(ull*)(hsH + b*136 + k4*4) = tH[m];
        *(ull*)(hsL + b*136 + k4*4) = tL[m];
      }
      __syncthreads();
      f32x4 acc[2][4];
      #pragma unroll
      for (int bt=0;bt<2;++bt){
        #pragma unroll
        for (int ct=0;ct<4;++ct) acc[bt][ct]=xpf[bt][ct];
      }
      #pragma unroll
      for (int kt=0;kt<4;++kt){
        short8 ah[2], al[2];
        #pragma unroll
        for (int bt=0;bt<2;++bt){
          int off = (bt*16+lr)*136 + kt*32 + lk;
          ah[bt] = *(const short8*)(hsH + off);
          al[bt] = *(const short8*)(hsL + off);
        }
        #pragma unroll
        for (int bt=0;bt<2;++bt){
          #pragma unroll
          for (int ct=0;ct<4;++ct){
            acc[bt][ct] = __builtin_amdgcn_mfma_f32_16x16x32_bf16(ah[bt], bhi[kt][ct], acc[bt][ct],0,0,0);
            acc[bt][ct] = __builtin_amdgcn_mfma_f32_16x16x32_bf16(al[bt], bhi[kt][ct], acc[bt][ct],0,0,0);
            acc[bt][ct] = __builtin_amdgcn_mfma_f32_16x16x32_bf16(ah[bt], blo[kt][ct], acc[bt][ct],0,0,0);
          }
        }
      }
      #pragma unroll
      for (int bt=0;bt<2;++bt){
        #pragma unroll
        for (int ct=0;ct<4;++ct){
          #pragma unroll
          for (int q=0;q<4;++q)
            gl[(bt*16 + (l>>4)*4 + q)*260 + wv*64 + ct*16 + lr] = acc[bt][ct][q];
        }
      }
      __syncthreads();
      float hv[8];
      #pragma unroll
      for (int j=0;j<8;++j){
        f32x4 gv = *(const f32x4*)&gl[nb*260 + (lu0+j)*4];
        float ig = sigm(gv[0]), fg = sigm(gv[1]);
        float gg = tanh_(gv[2]), og = sigm(gv[3]);
        c1[j] = fg*c1[j] + ig*gg;
        hv[j] = og*tanh_(c1[j]);
      }
      ushort hb[8], lb[8];
      #pragma unroll
      for (int j=0;j<8;++j){
        hb[j] = f2bf(hv[j]);
        float hf = __uint_as_float((unsigned)hb[j]<<16);
        lb[j] = f2bf(hv[j]-hf);
      }
      size_t db = (size_t)wb*8192 + (size_t)(gb0+nb)*32 + ((u0+lu0)>>2);
      ast8(h1hi+db,   pk4(hb[0],hb[1],hb[2],hb[3]));
      ast8(h1hi+db+1, pk4(hb[4],hb[5],hb[6],hb[7]));
      ast8(h1lo+db,   pk4(lb[0],lb[1],lb[2],lb[3]));
      ast8(h1lo+db+1, pk4(lb[4],lb[5],lb[6],lb[7]));
      flag_done(gf, role, t, r+1);
    }
  } else {
    // ================= layer-2 WG: 32 units, 32 batches =================
    const int us = role - 2;
    const int u0 = us * 32;
    ushort* hcH = (ushort*)sm;             // [32][392] bf16
    ushort* hcL = (ushort*)(sm + 25088);   // [32][392]
    float*  gl  = (float*)(sm + 50176);    // [32][132] f32 gates

    short8 bhi[12][2], blo[12][2];
    #pragma unroll
    for (int kt=0;kt<12;++kt){
      #pragma unroll
      for (int ct=0;ct<2;++ct){
        int col = wv*32 + ct*16 + lr;
        int lu = col>>2, g = col&3;
        int row = g*H2 + u0 + lu;
        const float* src = (kt<4) ? (Wih2 + (size_t)row*D + kt*32 + lk)
                                  : (Whh2 + (size_t)row*H2 + (kt-4)*32 + lk);
        short8 vh, vl;
        #pragma unroll
        for (int j=0;j<8;++j){
          float w = src[j];
          ushort hb = f2bf(w);
          float hf = __uint_as_float((unsigned)hb<<16);
          vh[j] = (short)hb; vl[j] = (short)f2bf(w - hf);
        }
        bhi[kt][ct]=vh; blo[kt][ct]=vl;
      }
    }
    float biasv[2];
    #pragma unroll
    for (int ct=0;ct<2;++ct){
      int col = wv*32 + ct*16 + lr;
      int lu = col>>2, g = col&3;
      biasv[ct] = bih2[g*H2+u0+lu] + bhh2[g*H2+u0+lu];
    }
    const int nb = t>>3, lu0 = (t&7)*4;
    float wo[4];
    #pragma unroll
    for (int j=0;j<4;++j) wo[j] = Wout[u0+lu0+j];
    float c2[4] = {0.f,0.f,0.f,0.f};

    for (int rr=0; rr<=S; ++rr){
      if (rr == 0){
        flag_done(gf, role, t, 1);
        continue;
      }
      wait_l2(gf, t, rr);
      const int ts = rr-1;
      const ull* s1H = h1hi + (size_t)((rr-1)&3)*8192;
      const ull* s1L = h1lo + (size_t)((rr-1)&3)*8192;
      const ull* s2H = h2hi + (size_t)((rr-2)&3)*16384;
      const ull* s2L = h2lo + (size_t)((rr-2)&3)*16384;
      // ---- single combined load batch (all 24 coherent loads overlap) ----
      ull t1H[4], t1L[4], t2H[8], t2L[8];
      #pragma unroll
      for (int m=0;m<4;++m){
        int id = t + m*256;
        int b = id>>5, s = id&31;
        size_t go = (size_t)(gb0+b)*32 + s;
        t1H[m] = ald8(s1H+go);
        t1L[m] = ald8(s1L+go);
      }
      #pragma unroll
      for (int m=0;m<8;++m){
        int id = t + m*256;
        int b = id>>6, s = id&63;
        size_t go = (size_t)(gb0+b)*64 + s;
        t2H[m] = ald8(s2H+go);
        t2L[m] = ald8(s2L+go);
      }
      #pragma unroll
      for (int m=0;m<4;++m){
        int id = t + m*256;
        int b = id>>5, s = id&31;
        *(ull*)(hcH + b*392 + s*4) = t1H[m];
        *(ull*)(hcL + b*392 + s*4) = t1L[m];
      }
      #pragma unroll
      for (int m=0;m<8;++m){
        int id = t + m*256;
        int b = id>>6, s = id&63;
        *(ull*)(hcH + b*392 + 128 + s*4) = t2H[m];
        *(ull*)(hcL + b*392 + 128 + s*4) = t2L[m];
      }
      __syncthreads();
      f32x4 acc[2][2];
      #pragma unroll
      for (int bt=0;bt<2;++bt){
        #pragma unroll
        for (int ct=0;ct<2;++ct){
          f32x4 a; a[0]=biasv[ct]; a[1]=biasv[ct]; a[2]=biasv[ct]; a[3]=biasv[ct];
          acc[bt][ct]=a;
        }
      }
      #pragma unroll
      for (int kt=0;kt<12;++kt){
        short8 ah[2], al[2];
        #pragma unroll
        for (int bt=0;bt<2;++bt){
          int off = (bt*16+lr)*392 + kt*32 + lk;
          ah[bt] = *(const short8*)(hcH + off);
          al[bt] = *(const short8*)(hcL + off);
        }
        #pragma unroll
        for (int bt=0;bt<2;++bt){
          #pragma unroll
          for (int ct=0;ct<2;++ct){
            acc[bt][ct] = __builtin_amdgcn_mfma_f32_16x16x32_bf16(ah[bt], bhi[kt][ct], acc[bt][ct],0,0,0);
            acc[bt][ct] = __builtin_amdgcn_mfma_f32_16x16x32_bf16(al[bt], bhi[kt][ct], acc[bt][ct],0,0,0);
            acc[bt][ct] = __builtin_amdgcn_mfma_f32_16x16x32_bf16(ah[bt], blo[kt][ct], acc[bt][ct],0,0,0);
          }
        }
      }
      #pragma unroll
      for (int bt=0;bt<2;++bt){
        #pragma unroll
        for (int ct=0;ct<2;++ct){
          #pragma unroll
          for (int q=0;q<4;++q)
            gl[(bt*16 + (l>>4)*4 + q)*132 + wv*32 + ct*16 + lr] = acc[bt][ct][q];
        }
      }
      __syncthreads();
      float psum = 0.f;
      ushort hb[4], lb[4];
      #pragma unroll
      for (int j=0;j<4;++j){
        f32x4 gv = *(const f32x4*)&gl[nb*132 + (lu0+j)*4];
        float ig = sigm(gv[0]), fg = sigm(gv[1]);
        float gg = tanh_(gv[2]), og = sigm(gv[3]);
        c2[j] = fg*c2[j] + ig*gg;
        float h = og*tanh_(c2[j]);
        psum += h*wo[j];
        hb[j] = f2bf(h);
        lb[j] = f2bf(h - __uint_as_float((unsigned)hb[j]<<16));
      }
      size_t db = (size_t)((rr-1)&3)*16384 + (size_t)(gb0+nb)*64 + ((u0+lu0)>>2);
      ast8(h2hi+db, pk4(hb[0],hb[1],hb[2],hb[3]));
      ast8(h2lo+db, pk4(lb[0],lb[1],lb[2],lb[3]));
      // publish FIRST (syncthreads drains all stores), outp store after
      flag_done(gf, role, t, rr+1);
      psum += __shfl_xor(psum,1,64);
      psum += __shfl_xor(psum,2,64);
      psum += __shfl_xor(psum,4,64);
      if ((t&7)==0) outp[(size_t)ts*2048 + us*256 + gb0+nb] = psum;
    }
  }
}

__global__ void k_final(const char* __restrict__ wsb, const float* __restrict__ bout,
                        float* __restrict__ out){
  const float* outp = (const float*)(wsb + OFF_OUTP);
  int id = blockIdx.x*blockDim.x + threadIdx.x;
  if (id >= B*S) return;
  int tt = id >> 8;
  int b  = id & 255;
  float s = bout[0];
  const float* p = outp + (size_t)tt*2048 + b;
  #pragma unroll
  for (int u = 0; u < 8; ++u) s += p[(size_t)u*256];
  out[(size_t)b*S + tt] = s;
}

extern "C" void kernel_launch(void* const* d_in, const int* in_sizes, int n_in,
                              void* d_out, int out_size, void* d_ws, size_t ws_size,
                              hipStream_t stream){
  const float* x    = (const float*)d_in[0];
  const float* Wih1 = (const float*)d_in[1];
  const float* Whh1 = (const float*)d_in[2];
  const float* bih1 = (const float*)d_in[3];
  const float* bhh1 = (const float*)d_in[4];
  const float* Wih2 = (const float*)d_in[5];
  const float* Whh2 = (const float*)d_in[6];
  const float* bih2 = (const float*)d_in[7];
  const float* bhh2 = (const float*)d_in[8];
  const float* Wout = (const float*)d_in[9];
  const float* bout = (const float*)d_in[10];
  char* wsb  = (char*)d_ws;
  float* out = (float*)d_out;

  (void)hipFuncSetAttribute((const void*)k_persist,
                            hipFuncAttributeMaxDynamicSharedMemorySize, DYN_LDS);

  k_zero<<<dim3(64), dim3(256), 0, stream>>>(wsb);
  k_xproj<<<dim3(B), dim3(256), 0, stream>>>(x, Wih1, bih1, bhh1, wsb);
  k_persist<<<dim3(NWG), dim3(256), DYN_LDS, stream>>>(Whh1, Wih2, Whh2, bih2, bhh2, Wout, wsb);
  k_final<<<dim3((B*S)/256), dim3(256), 0, stream>>>(wsb, bout, out);
}

// Round 11
// 1852.972 us; speedup vs baseline: 1.3343x; 1.0635x over previous
//
#include <hip/hip_runtime.h>

#define S 512
#define B 256
#define D 128
#define H1 128
#define H2 256

#define BG 32
#define NWG 80

// byte offsets in ws
#define OFF_XPROJ 0u          // [B][512] f32 = 524288
#define OFF_H1HI  524288u     // [4][B][H1] bf16 = 262144
#define OFF_H1LO  786432u
#define OFF_H2HI  1048576u    // [4][B][H2] bf16 = 524288
#define OFF_H2LO  1572864u
#define OFF_OUTP  2097152u    // [S][8][B] f32 = 4194304
#define OFF_FLAG  6291456u    // 8 grp * 32 int (agent scope)

#define DYN_LDS 67072

typedef unsigned long long ull;
typedef unsigned short ushort;
typedef __attribute__((ext_vector_type(8))) short short8;
typedef __attribute__((ext_vector_type(4))) float f32x4;

__device__ __forceinline__ ushort f2bf(float f){
  unsigned u = __float_as_uint(f);
  unsigned r = u + 0x7fffu + ((u>>16)&1u);
  return (ushort)(r>>16);
}
__device__ __forceinline__ float rcpf_(float x){ return __builtin_amdgcn_rcpf(x); }
__device__ __forceinline__ float sigm(float x){ return rcpf_(1.f + __expf(-x)); }
__device__ __forceinline__ float tanh_(float x){ return 1.f - 2.f*rcpf_(1.f + __expf(2.f*x)); }
__device__ __forceinline__ ull pk4(ushort a, ushort b, ushort c, ushort d){
  return (ull)a | ((ull)b<<16) | ((ull)c<<32) | ((ull)d<<48);
}

__device__ __forceinline__ int aldi(const int* p){
  return __hip_atomic_load(p, __ATOMIC_RELAXED, __HIP_MEMORY_SCOPE_AGENT);
}
__device__ __forceinline__ void asti(int* p, int v){
  __hip_atomic_store(p, v, __ATOMIC_RELAXED, __HIP_MEMORY_SCOPE_AGENT);
}
__device__ __forceinline__ ull ald8(const ull* p){
  return __hip_atomic_load(p, __ATOMIC_RELAXED, __HIP_MEMORY_SCOPE_AGENT);
}
__device__ __forceinline__ void ast8(ull* p, ull v){
  __hip_atomic_store(p, v, __ATOMIC_RELAXED, __HIP_MEMORY_SCOPE_AGENT);
}
__device__ __forceinline__ void drain_vm(){
  asm volatile("s_waitcnt vmcnt(0)" ::: "memory");
  __builtin_amdgcn_sched_barrier(0);
}

// ---------------- init kernels ----------------
__global__ void k_zero(char* wsb){
  long long id = (long long)blockIdx.x*blockDim.x + threadIdx.x;
  long long stride = (long long)gridDim.x*blockDim.x;
  ull* h = (ull*)(wsb + OFF_H1HI);
  for (long long i = id; i < 196608; i += stride) h[i] = 0ull;
  ull* f = (ull*)(wsb + OFF_FLAG);
  for (long long i = id; i < 128; i += stride) f[i] = 0ull;
}

__global__ void k_xproj(const float* __restrict__ x, const float* __restrict__ Wih1,
                        const float* __restrict__ bih1, const float* __restrict__ bhh1,
                        char* __restrict__ wsb){
  __shared__ float xs[D];
  float* xproj = (float*)(wsb + OFF_XPROJ);
  int b = blockIdx.x;
  for (int d = threadIdx.x; d < D; d += blockDim.x) xs[d] = x[b*D + d];
  __syncthreads();
  for (int g = threadIdx.x; g < 4*H1; g += blockDim.x){
    float acc = bih1[g] + bhh1[g];
    const float* w = &Wih1[(size_t)g*D];
    #pragma unroll 8
    for (int d = 0; d < D; ++d) acc += xs[d]*w[d];
    xproj[(size_t)b*512 + g] = acc;
  }
}

// ---------------- persistent kernel ----------------
__global__ void __launch_bounds__(256,1)
k_persist(const float* __restrict__ Whh1,
          const float* __restrict__ Wih2, const float* __restrict__ Whh2,
          const float* __restrict__ bih2, const float* __restrict__ bhh2,
          const float* __restrict__ Wout,
          char* __restrict__ wsb){
  extern __shared__ char sm[];
  const int wg = blockIdx.x;
  const int t  = threadIdx.x;
  const int grp = wg & 7, role = wg >> 3;     // wg = role*8 + grp
  const int gb0 = grp * BG;
  const int l = t & 63, wv = t >> 6, lr = l & 15, lk = (l >> 4) * 8;

  float* xproj = (float*)(wsb + OFF_XPROJ);
  ull* h1hi = (ull*)(wsb + OFF_H1HI);   // [4][B][H1] -> 8192 ull per buf
  ull* h1lo = (ull*)(wsb + OFF_H1LO);
  ull* h2hi = (ull*)(wsb + OFF_H2HI);   // [4][B][H2] -> 16384 ull per buf
  ull* h2lo = (ull*)(wsb + OFF_H2LO);
  float* outp = (float*)(wsb + OFF_OUTP);
  int* gf = (int*)(wsb + OFF_FLAG) + grp*32;

  if (role < 2){
    // ================= layer-1 WG: 64 units, 32 batches =================
    const int u0 = role * 64;
    ushort* hsH = (ushort*)sm;            // [32][136]
    ushort* hsL = (ushort*)(sm + 8704);
    float*  gl  = (float*)(sm + 17408);   // [32][260]
    short8 bhi[4][4], blo[4][4];
    #pragma unroll
    for (int kt=0;kt<4;++kt){
      #pragma unroll
      for (int ct=0;ct<4;++ct){
        int col = wv*64 + ct*16 + lr;
        int lu = col>>2, g = col&3;
        const float* src = Whh1 + (size_t)(g*H1 + u0 + lu)*D + kt*32 + lk;
        short8 vh, vl;
        #pragma unroll
        for (int j=0;j<8;++j){
          float w = src[j];
          ushort hbv = f2bf(w);
          float hf = __uint_as_float((unsigned)hbv<<16);
          vh[j] = (short)hbv; vl[j] = (short)f2bf(w - hf);
        }
        bhi[kt][ct]=vh; blo[kt][ct]=vl;
      }
    }
    f32x4 xpf[2][4];
    #pragma unroll
    for (int bt=0;bt<2;++bt){
      #pragma unroll
      for (int ct=0;ct<4;++ct){
        int col = wv*64 + ct*16 + lr;
        int lu = col>>2, g = col&3;
        #pragma unroll
        for (int q=0;q<4;++q){
          int b = gb0 + bt*16 + (l>>4)*4 + q;
          xpf[bt][ct][q] = xproj[(size_t)b*512 + g*H1 + u0 + lu];
        }
      }
    }
    const int nb = t>>3, lu0 = (t&7)*8;
    float c1[8] = {0.f,0.f,0.f,0.f,0.f,0.f,0.f,0.f};
    int lastf = (t<10) ? 0 : 0x7fffffff;
    int bud = 1<<21;

    for (int r=0; r<S; ++r){
      if (r>0){
        if (t < 64){
          int need = (t<2) ? r : (r-2);
          if (!__all((t<10) ? (lastf>=need) : true)){
            for(;;){
              if (t<10) lastf = aldi(&gf[t]);
              if (__all((t<10) ? (lastf>=need) : true)) break;
              if (--bud < 0) break;
              __builtin_amdgcn_s_sleep(1);
            }
          }
        }
        __syncthreads();
      }
      const int rb = (r-1)&3, wb = r&3;
      const ull* sH = h1hi + (size_t)rb*8192;
      const ull* sL = h1lo + (size_t)rb*8192;
      ull tH[4], tL[4];
      #pragma unroll
      for (int m=0;m<4;++m){
        int id = t + m*256;
        int b = id>>5, k4 = id&31;
        size_t go = (size_t)(gb0+b)*32 + k4;
        tH[m] = ald8(sH+go);
        tL[m] = ald8(sL+go);
      }
      drain_vm();
      #pragma unroll
      for (int m=0;m<4;++m){
        int id = t + m*256;
        int b = id>>5, k4 = id&31;
        *(ull*)(hsH + b*136 + k4*4) = tH[m];
        *(ull*)(hsL + b*136 + k4*4) = tL[m];
      }
      __syncthreads();
      f32x4 acc[2][4];
      #pragma unroll
      for (int bt=0;bt<2;++bt){
        #pragma unroll
        for (int ct=0;ct<4;++ct) acc[bt][ct]=xpf[bt][ct];
      }
      #pragma unroll
      for (int kt=0;kt<4;++kt){
        short8 ah[2], al[2];
        #pragma unroll
        for (int bt=0;bt<2;++bt){
          int off = (bt*16+lr)*136 + kt*32 + lk;
          ah[bt] = *(const short8*)(hsH + off);
          al[bt] = *(const short8*)(hsL + off);
        }
        #pragma unroll
        for (int bt=0;bt<2;++bt){
          #pragma unroll
          for (int ct=0;ct<4;++ct){
            acc[bt][ct] = __builtin_amdgcn_mfma_f32_16x16x32_bf16(ah[bt], bhi[kt][ct], acc[bt][ct],0,0,0);
            acc[bt][ct] = __builtin_amdgcn_mfma_f32_16x16x32_bf16(al[bt], bhi[kt][ct], acc[bt][ct],0,0,0);
            acc[bt][ct] = __builtin_amdgcn_mfma_f32_16x16x32_bf16(ah[bt], blo[kt][ct], acc[bt][ct],0,0,0);
          }
        }
      }
      #pragma unroll
      for (int bt=0;bt<2;++bt){
        #pragma unroll
        for (int ct=0;ct<4;++ct){
          #pragma unroll
          for (int q=0;q<4;++q)
            gl[(bt*16 + (l>>4)*4 + q)*260 + wv*64 + ct*16 + lr] = acc[bt][ct][q];
        }
      }
      __syncthreads();
      float hv[8];
      #pragma unroll
      for (int j=0;j<8;++j){
        f32x4 gv = *(const f32x4*)&gl[nb*260 + (lu0+j)*4];
        float ig = sigm(gv[0]), fg = sigm(gv[1]);
        float gg = tanh_(gv[2]), og = sigm(gv[3]);
        c1[j] = fg*c1[j] + ig*gg;
        hv[j] = og*tanh_(c1[j]);
      }
      ushort hb[8], lb[8];
      #pragma unroll
      for (int j=0;j<8;++j){
        hb[j] = f2bf(hv[j]);
        float hf = __uint_as_float((unsigned)hb[j]<<16);
        lb[j] = f2bf(hv[j]-hf);
      }
      size_t db = (size_t)wb*8192 + (size_t)(gb0+nb)*32 + ((u0+lu0)>>2);
      ast8(h1hi+db,   pk4(hb[0],hb[1],hb[2],hb[3]));
      ast8(h1hi+db+1, pk4(hb[4],hb[5],hb[6],hb[7]));
      ast8(h1lo+db,   pk4(lb[0],lb[1],lb[2],lb[3]));
      ast8(h1lo+db+1, pk4(lb[4],lb[5],lb[6],lb[7]));
      drain_vm();
      __syncthreads();
      if (t == 0) asti(&gf[role], r+1);
    }
  } else {
    // ================= layer-2 WG: 32 units, 32 batches =================
    const int us = role - 2;
    const int u0 = us * 32;
    ushort* hcH = (ushort*)sm;             // [32][392]
    ushort* hcL = (ushort*)(sm + 25088);
    float*  gl  = (float*)(sm + 50176);    // [32][132]
    short8 bhi[12][2], blo[12][2];
    #pragma unroll
    for (int kt=0;kt<12;++kt){
      #pragma unroll
      for (int ct=0;ct<2;++ct){
        int col = wv*32 + ct*16 + lr;
        int lu = col>>2, g = col&3;
        int row = g*H2 + u0 + lu;
        const float* src = (kt<4) ? (Wih2 + (size_t)row*D + kt*32 + lk)
                                  : (Whh2 + (size_t)row*H2 + (kt-4)*32 + lk);
        short8 vh, vl;
        #pragma unroll
        for (int j=0;j<8;++j){
          float w = src[j];
          ushort hbv = f2bf(w);
          float hf = __uint_as_float((unsigned)hbv<<16);
          vh[j] = (short)hbv; vl[j] = (short)f2bf(w - hf);
        }
        bhi[kt][ct]=vh; blo[kt][ct]=vl;
      }
    }
    float biasv[2];
    #pragma unroll
    for (int ct=0;ct<2;++ct){
      int col = wv*32 + ct*16 + lr;
      int lu = col>>2, g = col&3;
      biasv[ct] = bih2[g*H2+u0+lu] + bhh2[g*H2+u0+lu];
    }
    const int nb = t>>3, lu0 = (t&7)*4;
    float wo[4];
    #pragma unroll
    for (int j=0;j<4;++j) wo[j] = Wout[u0+lu0+j];
    float c2[4] = {0.f,0.f,0.f,0.f};
    int lastf = (t<10) ? 0 : 0x7fffffff;
    int bud = 1<<21;

    // round 0: publish initial flag
    __syncthreads();
    if (t == 0) asti(&gf[role], 1);

    for (int rr=1; rr<=S; ++rr){
      const int ts = rr-1;
      // ---- gate on L1 flags only (cached; L1 runs 2 ahead -> usually free) ----
      if (t < 64){
        if (!__all((t<2) ? (lastf>=rr) : true)){
          for(;;){
            if (t<10) lastf = aldi(&gf[t]);
            if (__all((t<2) ? (lastf>=rr) : true)) break;
            if (--bud < 0) break;
            __builtin_amdgcn_s_sleep(1);
          }
        }
      }
      __syncthreads();
      // ---- issue h1 loads immediately ----
      const ull* s1H = h1hi + (size_t)((rr-1)&3)*8192;
      const ull* s1L = h1lo + (size_t)((rr-1)&3)*8192;
      ull t1H[4], t1L[4];
      #pragma unroll
      for (int m=0;m<4;++m){
        int id = t + m*256;
        int b = id>>5, s = id&31;
        size_t go = (size_t)(gb0+b)*32 + s;
        t1H[m] = ald8(s1H+go);
        t1L[m] = ald8(s1L+go);
      }
      // ---- wave0 polls peer h2 flags while all waves drain+stage h1 ----
      if (t < 64){
        if (!__all((t>=2 && t<10) ? (lastf>=rr) : true)){
          for(;;){
            if (t<10) lastf = aldi(&gf[t]);
            if (__all((t>=2 && t<10) ? (lastf>=rr) : true)) break;
            if (--bud < 0) break;
            __builtin_amdgcn_s_sleep(1);
          }
        }
      }
      drain_vm();
      #pragma unroll
      for (int m=0;m<4;++m){
        int id = t + m*256;
        int b = id>>5, s = id&31;
        *(ull*)(hcH + b*392 + s*4) = t1H[m];
        *(ull*)(hcL + b*392 + s*4) = t1L[m];
      }
      __syncthreads();
      // ---- issue h2 loads; latency hides under MFMA-A ----
      const ull* s2H = h2hi + (size_t)((rr-2)&3)*16384;
      const ull* s2L = h2lo + (size_t)((rr-2)&3)*16384;
      ull t2H[8], t2L[8];
      #pragma unroll
      for (int m=0;m<8;++m){
        int id = t + m*256;
        int b = id>>6, s = id&63;
        size_t go = (size_t)(gb0+b)*64 + s;
        t2H[m] = ald8(s2H+go);
        t2L[m] = ald8(s2L+go);
      }
      // ---- MFMA-A: Wih2 x h1 (4 kt) ----
      f32x4 acc[2][2];
      #pragma unroll
      for (int bt=0;bt<2;++bt){
        #pragma unroll
        for (int ct=0;ct<2;++ct){
          f32x4 a; a[0]=biasv[ct]; a[1]=biasv[ct]; a[2]=biasv[ct]; a[3]=biasv[ct];
          acc[bt][ct]=a;
        }
      }
      #pragma unroll
      for (int kt=0;kt<4;++kt){
        short8 ah[2], al[2];
        #pragma unroll
        for (int bt=0;bt<2;++bt){
          int off = (bt*16+lr)*392 + kt*32 + lk;
          ah[bt] = *(const short8*)(hcH + off);
          al[bt] = *(const short8*)(hcL + off);
        }
        #pragma unroll
        for (int bt=0;bt<2;++bt){
          #pragma unroll
          for (int ct=0;ct<2;++ct){
            acc[bt][ct] = __builtin_amdgcn_mfma_f32_16x16x32_bf16(ah[bt], bhi[kt][ct], acc[bt][ct],0,0,0);
            acc[bt][ct] = __builtin_amdgcn_mfma_f32_16x16x32_bf16(al[bt], bhi[kt][ct], acc[bt][ct],0,0,0);
            acc[bt][ct] = __builtin_amdgcn_mfma_f32_16x16x32_bf16(ah[bt], blo[kt][ct], acc[bt][ct],0,0,0);
          }
        }
      }
      // ---- stage h2, MFMA-B: Whh2 x h2 (8 kt) ----
      drain_vm();
      #pragma unroll
      for (int m=0;m<8;++m){
        int id = t + m*256;
        int b = id>>6, s = id&63;
        *(ull*)(hcH + b*392 + 128 + s*4) = t2H[m];
        *(ull*)(hcL + b*392 + 128 + s*4) = t2L[m];
      }
      __syncthreads();
      #pragma unroll
      for (int kt=4;kt<12;++kt){
        short8 ah[2], al[2];
        #pragma unroll
        for (int bt=0;bt<2;++bt){
          int off = (bt*16+lr)*392 + kt*32 + lk;
          ah[bt] = *(const short8*)(hcH + off);
          al[bt] = *(const short8*)(hcL + off);
        }
        #pragma unroll
        for (int bt=0;bt<2;++bt){
          #pragma unroll
          for (int ct=0;ct<2;++ct){
            acc[bt][ct] = __builtin_amdgcn_mfma_f32_16x16x32_bf16(ah[bt], bhi[kt][ct], acc[bt][ct],0,0,0);
            acc[bt][ct] = __builtin_amdgcn_mfma_f32_16x16x32_bf16(al[bt], bhi[kt][ct], acc[bt][ct],0,0,0);
            acc[bt][ct] = __builtin_amdgcn_mfma_f32_16x16x32_bf16(ah[bt], blo[kt][ct], acc[bt][ct],0,0,0);
          }
        }
      }
      #pragma unroll
      for (int bt=0;bt<2;++bt){
        #pragma unroll
        for (int ct=0;ct<2;++ct){
          #pragma unroll
          for (int q=0;q<4;++q)
            gl[(bt*16 + (l>>4)*4 + q)*132 + wv*32 + ct*16 + lr] = acc[bt][ct][q];
        }
      }
      __syncthreads();
      float psum = 0.f;
      ushort hb[4], lb[4];
      #pragma unroll
      for (int j=0;j<4;++j){
        f32x4 gv = *(const f32x4*)&gl[nb*132 + (lu0+j)*4];
        float ig = sigm(gv[0]), fg = sigm(gv[1]);
        float gg = tanh_(gv[2]), og = sigm(gv[3]);
        c2[j] = fg*c2[j] + ig*gg;
        float h = og*tanh_(c2[j]);
        psum += h*wo[j];
        hb[j] = f2bf(h);
        lb[j] = f2bf(h - __uint_as_float((unsigned)hb[j]<<16));
      }
      size_t db = (size_t)((rr-1)&3)*16384 + (size_t)(gb0+nb)*64 + ((u0+lu0)>>2);
      ast8(h2hi+db, pk4(hb[0],hb[1],hb[2],hb[3]));
      ast8(h2lo+db, pk4(lb[0],lb[1],lb[2],lb[3]));
      // overlap store-ack with psum reduction + outp store
      psum += __shfl_xor(psum,1,64);
      psum += __shfl_xor(psum,2,64);
      psum += __shfl_xor(psum,4,64);
      if ((t&7)==0) outp[(size_t)ts*2048 + us*256 + gb0+nb] = psum;
      drain_vm();
      __syncthreads();
      if (t == 0) asti(&gf[role], rr+1);
    }
  }
}

__global__ void k_final(const char* __restrict__ wsb, const float* __restrict__ bout,
                        float* __restrict__ out){
  const float* outp = (const float*)(wsb + OFF_OUTP);
  int id = blockIdx.x*blockDim.x + threadIdx.x;
  if (id >= B*S) return;
  int tt = id >> 8;
  int b  = id & 255;
  float s = bout[0];
  const float* p = outp + (size_t)tt*2048 + b;
  #pragma unroll
  for (int u = 0; u < 8; ++u) s += p[(size_t)u*256];
  out[(size_t)b*S + tt] = s;
}

extern "C" void kernel_launch(void* const* d_in, const int* in_sizes, int n_in,
                              void* d_out, int out_size, void* d_ws, size_t ws_size,
                              hipStream_t stream){
  const float* x    = (const float*)d_in[0];
  const float* Wih1 = (const float*)d_in[1];
  const float* Whh1 = (const float*)d_in[2];
  const float* bih1 = (const float*)d_in[3];
  const float* bhh1 = (const float*)d_in[4];
  const float* Wih2 = (const float*)d_in[5];
  const float* Whh2 = (const float*)d_in[6];
  const float* bih2 = (const float*)d_in[7];
  const float* bhh2 = (const float*)d_in[8];
  const float* Wout = (const float*)d_in[9];
  const float* bout = (const float*)d_in[10];
  char* wsb  = (char*)d_ws;
  float* out = (float*)d_out;

  (void)hipFuncSetAttribute((const void*)k_persist,
                            hipFuncAttributeMaxDynamicSharedMemorySize, DYN_LDS);

  k_zero<<<dim3(64), dim3(256), 0, stream>>>(wsb);
  k_xproj<<<dim3(B), dim3(256), 0, stream>>>(x, Wih1, bih1, bhh1, wsb);
  k_persist<<<dim3(NWG), dim3(256), DYN_LDS, stream>>>(Whh1, Wih2, Whh2, bih2, bhh2, Wout, wsb);
  k_final<<<dim3((B*S)/256), dim3(256), 0, stream>>>(wsb, bout, out);
}

// Round 12
// 1748.962 us; speedup vs baseline: 1.4136x; 1.0595x over previous
//
#include <hip/hip_runtime.h>

#define S 512
#define B 256
#define D 128
#define H1 128
#define H2 256

#define BG 32
#define NWG 80

// byte offsets in ws
#define OFF_XPROJ 0u          // [B][512] f32 = 524288
#define OFF_H1C   524288u     // [4][B][32] 16B chunks (hi|lo interleaved) = 524288
#define OFF_H2C   1048576u    // [4][B][64] 16B chunks = 1048576
#define OFF_OUTP  2097152u    // [S][8][B] f32 = 4194304
#define OFF_FLAG  6291456u    // 8 grp * 32 int (agent scope)

#define DYN_LDS 67072

typedef unsigned long long ull;
typedef unsigned short ushort;
typedef unsigned int uint;
typedef __attribute__((ext_vector_type(8))) short short8;
typedef __attribute__((ext_vector_type(4))) float f32x4;
typedef __attribute__((ext_vector_type(4))) uint u32x4;

__device__ __forceinline__ ushort f2bf(float f){
  unsigned u = __float_as_uint(f);
  unsigned r = u + 0x7fffu + ((u>>16)&1u);
  return (ushort)(r>>16);
}
__device__ __forceinline__ float rcpf_(float x){ return __builtin_amdgcn_rcpf(x); }
__device__ __forceinline__ float sigm(float x){ return rcpf_(1.f + __expf(-x)); }
__device__ __forceinline__ float tanh_(float x){ return 1.f - 2.f*rcpf_(1.f + __expf(2.f*x)); }

__device__ __forceinline__ int aldi(const int* p){
  return __hip_atomic_load(p, __ATOMIC_RELAXED, __HIP_MEMORY_SCOPE_AGENT);
}
__device__ __forceinline__ void asti(int* p, int v){
  __hip_atomic_store(p, v, __ATOMIC_RELAXED, __HIP_MEMORY_SCOPE_AGENT);
}
// 16B uncached (L1+L2 bypass -> L3 coherence point) load/store
__device__ __forceinline__ u32x4 ld16(const u32x4* p){
  u32x4 v;
  asm volatile("global_load_dwordx4 %0, %1, off sc0 sc1"
               : "=v"(v) : "v"((ull)(size_t)p));
  return v;
}
__device__ __forceinline__ void st16(u32x4* p, u32x4 v){
  asm volatile("global_store_dwordx4 %0, %1, off sc0 sc1"
               :: "v"((ull)(size_t)p), "v"(v) : "memory");
}
__device__ __forceinline__ void drain_vm(){
  asm volatile("s_waitcnt vmcnt(0)" ::: "memory");
  __builtin_amdgcn_sched_barrier(0);
}
__device__ __forceinline__ ull lo64(u32x4 v){ return ((ull)v.y<<32) | v.x; }
__device__ __forceinline__ ull hi64(u32x4 v){ return ((ull)v.w<<32) | v.z; }

// ---------------- init kernels ----------------
__global__ void k_zero(char* wsb){
  long long id = (long long)blockIdx.x*blockDim.x + threadIdx.x;
  long long stride = (long long)gridDim.x*blockDim.x;
  ull* h = (ull*)(wsb + OFF_H1C);      // h1c + h2c contiguous = 1572864 B
  for (long long i = id; i < 196608; i += stride) h[i] = 0ull;
  ull* f = (ull*)(wsb + OFF_FLAG);
  for (long long i = id; i < 128; i += stride) f[i] = 0ull;
}

__global__ void k_xproj(const float* __restrict__ x, const float* __restrict__ Wih1,
                        const float* __restrict__ bih1, const float* __restrict__ bhh1,
                        char* __restrict__ wsb){
  __shared__ float xs[D];
  float* xproj = (float*)(wsb + OFF_XPROJ);
  int b = blockIdx.x;
  for (int d = threadIdx.x; d < D; d += blockDim.x) xs[d] = x[b*D + d];
  __syncthreads();
  for (int g = threadIdx.x; g < 4*H1; g += blockDim.x){
    float acc = bih1[g] + bhh1[g];
    const float* w = &Wih1[(size_t)g*D];
    #pragma unroll 8
    for (int d = 0; d < D; ++d) acc += xs[d]*w[d];
    xproj[(size_t)b*512 + g] = acc;
  }
}

// ---------------- persistent kernel ----------------
__global__ void __launch_bounds__(256,1)
k_persist(const float* __restrict__ Whh1,
          const float* __restrict__ Wih2, const float* __restrict__ Whh2,
          const float* __restrict__ bih2, const float* __restrict__ bhh2,
          const float* __restrict__ Wout,
          char* __restrict__ wsb){
  extern __shared__ char sm[];
  const int wg = blockIdx.x;
  const int t  = threadIdx.x;
  const int grp = wg & 7, role = wg >> 3;     // wg = role*8 + grp (XCD-local groups)
  const int gb0 = grp * BG;
  const int l = t & 63, wv = t >> 6, lr = l & 15, lk = (l >> 4) * 8;

  float* xproj = (float*)(wsb + OFF_XPROJ);
  u32x4* h1c = (u32x4*)(wsb + OFF_H1C);   // [4][B][32] chunks; 8192 chunks/buf
  u32x4* h2c = (u32x4*)(wsb + OFF_H2C);   // [4][B][64] chunks; 16384 chunks/buf
  float* outp = (float*)(wsb + OFF_OUTP);
  int* gf = (int*)(wsb + OFF_FLAG) + grp*32;

  if (role < 2){
    // ================= layer-1 WG: 64 units, 32 batches =================
    const int u0 = role * 64;
    ushort* hsH = (ushort*)sm;            // [32][136]
    ushort* hsL = (ushort*)(sm + 8704);
    float*  gl  = (float*)(sm + 17408);   // [32][260]
    short8 bhi[4][4], blo[4][4];
    #pragma unroll
    for (int kt=0;kt<4;++kt){
      #pragma unroll
      for (int ct=0;ct<4;++ct){
        int col = wv*64 + ct*16 + lr;
        int lu = col>>2, g = col&3;
        const float* src = Whh1 + (size_t)(g*H1 + u0 + lu)*D + kt*32 + lk;
        short8 vh, vl;
        #pragma unroll
        for (int j=0;j<8;++j){
          float w = src[j];
          ushort hbv = f2bf(w);
          float hf = __uint_as_float((unsigned)hbv<<16);
          vh[j] = (short)hbv; vl[j] = (short)f2bf(w - hf);
        }
        bhi[kt][ct]=vh; blo[kt][ct]=vl;
      }
    }
    f32x4 xpf[2][4];
    #pragma unroll
    for (int bt=0;bt<2;++bt){
      #pragma unroll
      for (int ct=0;ct<4;++ct){
        int col = wv*64 + ct*16 + lr;
        int lu = col>>2, g = col&3;
        #pragma unroll
        for (int q=0;q<4;++q){
          int b = gb0 + bt*16 + (l>>4)*4 + q;
          xpf[bt][ct][q] = xproj[(size_t)b*512 + g*H1 + u0 + lu];
        }
      }
    }
    const int nb = t>>3, lu0 = (t&7)*8;
    float c1[8] = {0.f,0.f,0.f,0.f,0.f,0.f,0.f,0.f};
    int lastf = (t<10) ? 0 : 0x7fffffff;
    int bud = 1<<21;

    for (int r=0; r<S; ++r){
      if (r>0){
        if (t < 64){
          int need = (t<2) ? r : (r-2);
          if (!__all((t<10) ? (lastf>=need) : true)){
            for(;;){
              if (t<10) lastf = aldi(&gf[t]);
              if (__all((t<10) ? (lastf>=need) : true)) break;
              if (--bud < 0) break;
              __builtin_amdgcn_s_sleep(1);
            }
          }
        }
        __syncthreads();
      }
      const int rb = (r-1)&3, wb = r&3;
      const u32x4* sB = h1c + (size_t)rb*8192;
      u32x4 tv[4];
      #pragma unroll
      for (int m=0;m<4;++m){
        int id = t + m*256;
        int b = id>>5, c = id&31;
        tv[m] = ld16(&sB[(size_t)(gb0+b)*32 + c]);
      }
      drain_vm();
      #pragma unroll
      for (int m=0;m<4;++m){
        int id = t + m*256;
        int b = id>>5, c = id&31;
        *(ull*)(hsH + b*136 + c*4) = lo64(tv[m]);
        *(ull*)(hsL + b*136 + c*4) = hi64(tv[m]);
      }
      __syncthreads();
      f32x4 acc[2][4];
      #pragma unroll
      for (int bt=0;bt<2;++bt){
        #pragma unroll
        for (int ct=0;ct<4;++ct) acc[bt][ct]=xpf[bt][ct];
      }
      #pragma unroll
      for (int kt=0;kt<4;++kt){
        short8 ah[2], al[2];
        #pragma unroll
        for (int bt=0;bt<2;++bt){
          int off = (bt*16+lr)*136 + kt*32 + lk;
          ah[bt] = *(const short8*)(hsH + off);
          al[bt] = *(const short8*)(hsL + off);
        }
        #pragma unroll
        for (int bt=0;bt<2;++bt){
          #pragma unroll
          for (int ct=0;ct<4;++ct){
            acc[bt][ct] = __builtin_amdgcn_mfma_f32_16x16x32_bf16(ah[bt], bhi[kt][ct], acc[bt][ct],0,0,0);
            acc[bt][ct] = __builtin_amdgcn_mfma_f32_16x16x32_bf16(al[bt], bhi[kt][ct], acc[bt][ct],0,0,0);
            acc[bt][ct] = __builtin_amdgcn_mfma_f32_16x16x32_bf16(ah[bt], blo[kt][ct], acc[bt][ct],0,0,0);
          }
        }
      }
      #pragma unroll
      for (int bt=0;bt<2;++bt){
        #pragma unroll
        for (int ct=0;ct<4;++ct){
          #pragma unroll
          for (int q=0;q<4;++q)
            gl[(bt*16 + (l>>4)*4 + q)*260 + wv*64 + ct*16 + lr] = acc[bt][ct][q];
        }
      }
      __syncthreads();
      float hv[8];
      #pragma unroll
      for (int j=0;j<8;++j){
        f32x4 gv = *(const f32x4*)&gl[nb*260 + (lu0+j)*4];
        float ig = sigm(gv[0]), fg = sigm(gv[1]);
        float gg = tanh_(gv[2]), og = sigm(gv[3]);
        c1[j] = fg*c1[j] + ig*gg;
        hv[j] = og*tanh_(c1[j]);
      }
      ushort hb[8], lb[8];
      #pragma unroll
      for (int j=0;j<8;++j){
        hb[j] = f2bf(hv[j]);
        float hf = __uint_as_float((unsigned)hb[j]<<16);
        lb[j] = f2bf(hv[j]-hf);
      }
      size_t db = (size_t)wb*8192 + (size_t)(gb0+nb)*32 + ((u0+lu0)>>2);
      u32x4 v0, v1;
      v0.x = (uint)hb[0] | ((uint)hb[1]<<16); v0.y = (uint)hb[2] | ((uint)hb[3]<<16);
      v0.z = (uint)lb[0] | ((uint)lb[1]<<16); v0.w = (uint)lb[2] | ((uint)lb[3]<<16);
      v1.x = (uint)hb[4] | ((uint)hb[5]<<16); v1.y = (uint)hb[6] | ((uint)hb[7]<<16);
      v1.z = (uint)lb[4] | ((uint)lb[5]<<16); v1.w = (uint)lb[6] | ((uint)lb[7]<<16);
      st16(&h1c[db],   v0);
      st16(&h1c[db+1], v1);
      drain_vm();
      __syncthreads();
      if (t == 0) asti(&gf[role], r+1);
    }
  } else {
    // ================= layer-2 WG: 32 units, 32 batches =================
    const int us = role - 2;
    const int u0 = us * 32;
    ushort* hcH = (ushort*)sm;             // [32][392]
    ushort* hcL = (ushort*)(sm + 25088);
    float*  gl  = (float*)(sm + 50176);    // [32][132]
    short8 bhi[12][2], blo[12][2];
    #pragma unroll
    for (int kt=0;kt<12;++kt){
      #pragma unroll
      for (int ct=0;ct<2;++ct){
        int col = wv*32 + ct*16 + lr;
        int lu = col>>2, g = col&3;
        int row = g*H2 + u0 + lu;
        const float* src = (kt<4) ? (Wih2 + (size_t)row*D + kt*32 + lk)
                                  : (Whh2 + (size_t)row*H2 + (kt-4)*32 + lk);
        short8 vh, vl;
        #pragma unroll
        for (int j=0;j<8;++j){
          float w = src[j];
          ushort hbv = f2bf(w);
          float hf = __uint_as_float((unsigned)hbv<<16);
          vh[j] = (short)hbv; vl[j] = (short)f2bf(w - hf);
        }
        bhi[kt][ct]=vh; blo[kt][ct]=vl;
      }
    }
    float biasv[2];
    #pragma unroll
    for (int ct=0;ct<2;++ct){
      int col = wv*32 + ct*16 + lr;
      int lu = col>>2, g = col&3;
      biasv[ct] = bih2[g*H2+u0+lu] + bhh2[g*H2+u0+lu];
    }
    const int nb = t>>3, lu0 = (t&7)*4;
    float wo[4];
    #pragma unroll
    for (int j=0;j<4;++j) wo[j] = Wout[u0+lu0+j];
    float c2[4] = {0.f,0.f,0.f,0.f};
    int lastf = (t<10) ? 0 : 0x7fffffff;
    int bud = 1<<21;

    __syncthreads();
    if (t == 0) asti(&gf[role], 1);

    for (int rr=1; rr<=S; ++rr){
      const int ts = rr-1;
      // ---- gate on L1 flags (cached; L1 runs 2 ahead -> usually free) ----
      if (t < 64){
        if (!__all((t<2) ? (lastf>=rr) : true)){
          for(;;){
            if (t<10) lastf = aldi(&gf[t]);
            if (__all((t<2) ? (lastf>=rr) : true)) break;
            if (--bud < 0) break;
            __builtin_amdgcn_s_sleep(1);
          }
        }
      }
      __syncthreads();
      // ---- issue h1 loads immediately ----
      const u32x4* s1 = h1c + (size_t)((rr-1)&3)*8192;
      u32x4 t1[4];
      #pragma unroll
      for (int m=0;m<4;++m){
        int id = t + m*256;
        int b = id>>5, c = id&31;
        t1[m] = ld16(&s1[(size_t)(gb0+b)*32 + c]);
      }
      // ---- wave0 polls peer h2 flags while loads fly ----
      if (t < 64){
        if (!__all((t>=2 && t<10) ? (lastf>=rr) : true)){
          for(;;){
            if (t<10) lastf = aldi(&gf[t]);
            if (__all((t>=2 && t<10) ? (lastf>=rr) : true)) break;
            if (--bud < 0) break;
            __builtin_amdgcn_s_sleep(1);
          }
        }
      }
      drain_vm();
      #pragma unroll
      for (int m=0;m<4;++m){
        int id = t + m*256;
        int b = id>>5, c = id&31;
        *(ull*)(hcH + b*392 + c*4) = lo64(t1[m]);
        *(ull*)(hcL + b*392 + c*4) = hi64(t1[m]);
      }
      __syncthreads();
      // ---- issue h2 loads; latency hides under MFMA-A ----
      const u32x4* s2 = h2c + (size_t)((rr-2)&3)*16384;
      u32x4 t2[8];
      #pragma unroll
      for (int m=0;m<8;++m){
        int id = t + m*256;
        int b = id>>6, c = id&63;
        t2[m] = ld16(&s2[(size_t)(gb0+b)*64 + c]);
      }
      // ---- MFMA-A: Wih2 x h1 (4 kt) ----
      f32x4 acc[2][2];
      #pragma unroll
      for (int bt=0;bt<2;++bt){
        #pragma unroll
        for (int ct=0;ct<2;++ct){
          f32x4 a; a[0]=biasv[ct]; a[1]=biasv[ct]; a[2]=biasv[ct]; a[3]=biasv[ct];
          acc[bt][ct]=a;
        }
      }
      #pragma unroll
      for (int kt=0;kt<4;++kt){
        short8 ah[2], al[2];
        #pragma unroll
        for (int bt=0;bt<2;++bt){
          int off = (bt*16+lr)*392 + kt*32 + lk;
          ah[bt] = *(const short8*)(hcH + off);
          al[bt] = *(const short8*)(hcL + off);
        }
        #pragma unroll
        for (int bt=0;bt<2;++bt){
          #pragma unroll
          for (int ct=0;ct<2;++ct){
            acc[bt][ct] = __builtin_amdgcn_mfma_f32_16x16x32_bf16(ah[bt], bhi[kt][ct], acc[bt][ct],0,0,0);
            acc[bt][ct] = __builtin_amdgcn_mfma_f32_16x16x32_bf16(al[bt], bhi[kt][ct], acc[bt][ct],0,0,0);
            acc[bt][ct] = __builtin_amdgcn_mfma_f32_16x16x32_bf16(ah[bt], blo[kt][ct], acc[bt][ct],0,0,0);
          }
        }
      }
      // ---- stage h2, MFMA-B: Whh2 x h2 (8 kt) ----
      drain_vm();
      #pragma unroll
      for (int m=0;m<8;++m){
        int id = t + m*256;
        int b = id>>6, c = id&63;
        *(ull*)(hcH + b*392 + 128 + c*4) = lo64(t2[m]);
        *(ull*)(hcL + b*392 + 128 + c*4) = hi64(t2[m]);
      }
      __syncthreads();
      #pragma unroll
      for (int kt=4;kt<12;++kt){
        short8 ah[2], al[2];
        #pragma unroll
        for (int bt=0;bt<2;++bt){
          int off = (bt*16+lr)*392 + kt*32 + lk;
          ah[bt] = *(const short8*)(hcH + off);
          al[bt] = *(const short8*)(hcL + off);
        }
        #pragma unroll
        for (int bt=0;bt<2;++bt){
          #pragma unroll
          for (int ct=0;ct<2;++ct){
            acc[bt][ct] = __builtin_amdgcn_mfma_f32_16x16x32_bf16(ah[bt], bhi[kt][ct], acc[bt][ct],0,0,0);
            acc[bt][ct] = __builtin_amdgcn_mfma_f32_16x16x32_bf16(al[bt], bhi[kt][ct], acc[bt][ct],0,0,0);
            acc[bt][ct] = __builtin_amdgcn_mfma_f32_16x16x32_bf16(ah[bt], blo[kt][ct], acc[bt][ct],0,0,0);
          }
        }
      }
      #pragma unroll
      for (int bt=0;bt<2;++bt){
        #pragma unroll
        for (int ct=0;ct<2;++ct){
          #pragma unroll
          for (int q=0;q<4;++q)
            gl[(bt*16 + (l>>4)*4 + q)*132 + wv*32 + ct*16 + lr] = acc[bt][ct][q];
        }
      }
      __syncthreads();
      float psum = 0.f;
      ushort hb[4], lb[4];
      #pragma unroll
      for (int j=0;j<4;++j){
        f32x4 gv = *(const f32x4*)&gl[nb*132 + (lu0+j)*4];
        float ig = sigm(gv[0]), fg = sigm(gv[1]);
        float gg = tanh_(gv[2]), og = sigm(gv[3]);
        c2[j] = fg*c2[j] + ig*gg;
        float h = og*tanh_(c2[j]);
        psum += h*wo[j];
        hb[j] = f2bf(h);
        lb[j] = f2bf(h - __uint_as_float((unsigned)hb[j]<<16));
      }
      size_t db = (size_t)((rr-1)&3)*16384 + (size_t)(gb0+nb)*64 + ((u0+lu0)>>2);
      u32x4 v0;
      v0.x = (uint)hb[0] | ((uint)hb[1]<<16); v0.y = (uint)hb[2] | ((uint)hb[3]<<16);
      v0.z = (uint)lb[0] | ((uint)lb[1]<<16); v0.w = (uint)lb[2] | ((uint)lb[3]<<16);
      st16(&h2c[db], v0);
      // overlap store-ack with psum reduction + outp store
      psum += __shfl_xor(psum,1,64);
      psum += __shfl_xor(psum,2,64);
      psum += __shfl_xor(psum,4,64);
      if ((t&7)==0) outp[(size_t)ts*2048 + us*256 + gb0+nb] = psum;
      drain_vm();
      __syncthreads();
      if (t == 0) asti(&gf[role], rr+1);
    }
  }
}

__global__ void k_final(const char* __restrict__ wsb, const float* __restrict__ bout,
                        float* __restrict__ out){
  const float* outp = (const float*)(wsb + OFF_OUTP);
  int id = blockIdx.x*blockDim.x + threadIdx.x;
  if (id >= B*S) return;
  int tt = id >> 8;
  int b  = id & 255;
  float s = bout[0];
  const float* p = outp + (size_t)tt*2048 + b;
  #pragma unroll
  for (int u = 0; u < 8; ++u) s += p[(size_t)u*256];
  out[(size_t)b*S + tt] = s;
}

extern "C" void kernel_launch(void* const* d_in, const int* in_sizes, int n_in,
                              void* d_out, int out_size, void* d_ws, size_t ws_size,
                              hipStream_t stream){
  const float* x    = (const float*)d_in[0];
  const float* Wih1 = (const float*)d_in[1];
  const float* Whh1 = (const float*)d_in[2];
  const float* bih1 = (const float*)d_in[3];
  const float* bhh1 = (const float*)d_in[4];
  const float* Wih2 = (const float*)d_in[5];
  const float* Whh2 = (const float*)d_in[6];
  const float* bih2 = (const float*)d_in[7];
  const float* bhh2 = (const float*)d_in[8];
  const float* Wout = (const float*)d_in[9];
  const float* bout = (const float*)d_in[10];
  char* wsb  = (char*)d_ws;
  float* out = (float*)d_out;

  (void)hipFuncSetAttribute((const void*)k_persist,
                            hipFuncAttributeMaxDynamicSharedMemorySize, DYN_LDS);

  k_zero<<<dim3(64), dim3(256), 0, stream>>>(wsb);
  k_xproj<<<dim3(B), dim3(256), 0, stream>>>(x, Wih1, bih1, bhh1, wsb);
  k_persist<<<dim3(NWG), dim3(256), DYN_LDS, stream>>>(Whh1, Wih2, Whh2, bih2, bhh2, Wout, wsb);
  k_final<<<dim3((B*S)/256), dim3(256), 0, stream>>>(wsb, bout, out);
}